// Round 14
// baseline (196.082 us; speedup 1.0000x reference)
//
#include <hip/hip_runtime.h>
#include <stdint.h>

#define BB 8
#define NN 2048
#define DD 128

typedef unsigned long long ull;
typedef unsigned int u32;
typedef unsigned short u16;
typedef __attribute__((ext_vector_type(8))) short bf16x8;
typedef __attribute__((ext_vector_type(4))) float f32x4;

// insertion into sorted-ascending 8-slot u64 register array (static indices only)
#define INS8(t8, cand) do { \
    t8[7] = (cand); ull _t; \
    if (t8[7] < t8[6]) { _t = t8[6]; t8[6] = t8[7]; t8[7] = _t; } \
    if (t8[6] < t8[5]) { _t = t8[5]; t8[5] = t8[6]; t8[6] = _t; } \
    if (t8[5] < t8[4]) { _t = t8[4]; t8[4] = t8[5]; t8[5] = _t; } \
    if (t8[4] < t8[3]) { _t = t8[3]; t8[3] = t8[4]; t8[4] = _t; } \
    if (t8[3] < t8[2]) { _t = t8[2]; t8[2] = t8[3]; t8[3] = _t; } \
    if (t8[2] < t8[1]) { _t = t8[1]; t8[1] = t8[2]; t8[2] = _t; } \
    if (t8[1] < t8[0]) { _t = t8[0]; t8[0] = t8[1]; t8[1] = _t; } \
  } while (0)

// compare-exchange (emits v_min_u32/v_max_u32, branchless)
#define CEX(a, b) do { u32 _lo = (a) < (b) ? (a) : (b); \
                       u32 _hi = (a) < (b) ? (b) : (a); \
                       (a) = _lo; (b) = _hi; } while (0)

// Batcher sort of 8 (19 CE): sort4 + sort4 + odd-even merge
#define SORT8(c) do { \
    CEX(c[0], c[1]); CEX(c[2], c[3]); CEX(c[0], c[2]); CEX(c[1], c[3]); CEX(c[1], c[2]); \
    CEX(c[4], c[5]); CEX(c[6], c[7]); CEX(c[4], c[6]); CEX(c[5], c[7]); CEX(c[5], c[6]); \
    CEX(c[0], c[4]); CEX(c[1], c[5]); CEX(c[2], c[6]); CEX(c[3], c[7]); \
    CEX(c[2], c[4]); CEX(c[3], c[5]); \
    CEX(c[1], c[2]); CEX(c[3], c[4]); CEX(c[5], c[6]); } while (0)

// t (sorted asc) := lowest-8 of union(t, s) (s sorted asc), sorted asc.
#define MERGE8(t, s) do { \
    u32 m0_ = (t)[0] < (s)[7] ? (t)[0] : (s)[7]; \
    u32 m1_ = (t)[1] < (s)[6] ? (t)[1] : (s)[6]; \
    u32 m2_ = (t)[2] < (s)[5] ? (t)[2] : (s)[5]; \
    u32 m3_ = (t)[3] < (s)[4] ? (t)[3] : (s)[4]; \
    u32 m4_ = (t)[4] < (s)[3] ? (t)[4] : (s)[3]; \
    u32 m5_ = (t)[5] < (s)[2] ? (t)[5] : (s)[2]; \
    u32 m6_ = (t)[6] < (s)[1] ? (t)[6] : (s)[1]; \
    u32 m7_ = (t)[7] < (s)[0] ? (t)[7] : (s)[0]; \
    CEX(m0_, m4_); CEX(m1_, m5_); CEX(m2_, m6_); CEX(m3_, m7_); \
    CEX(m0_, m2_); CEX(m1_, m3_); CEX(m4_, m6_); CEX(m5_, m7_); \
    CEX(m0_, m1_); CEX(m2_, m3_); CEX(m4_, m5_); CEX(m6_, m7_); \
    (t)[0] = m0_; (t)[1] = m1_; (t)[2] = m2_; (t)[3] = m3_; \
    (t)[4] = m4_; (t)[5] = m5_; (t)[6] = m6_; (t)[7] = m7_; \
  } while (0)

__device__ inline u16 f2bf_rn(float f) {
  uint32_t u = __float_as_uint(f);
  return (u16)((u + 0x7fffu + ((u >> 16) & 1u)) >> 16);
}

typedef __attribute__((address_space(1))) const void gvoid_t;
typedef __attribute__((address_space(3))) void lvoid_t;
__device__ __forceinline__ void gload16(const void* g, void* l) {
  __builtin_amdgcn_global_load_lds((gvoid_t*)g, (lvoid_t*)l, 16, 0, 0);
}

// ---------------- Kernel 1: fused  xx[row] = sum x^2  +  bf16 hi/lo split ----
__global__ __launch_bounds__(256) void k_cvx(const float* __restrict__ x,
                                             float* __restrict__ xx,
                                             u16* __restrict__ xh,
                                             u16* __restrict__ xl) {
  int row  = blockIdx.x * 4 + (threadIdx.x >> 6);
  int lane = threadIdx.x & 63;
  float2 v = *reinterpret_cast<const float2*>(x + (size_t)row * DD + lane * 2);
  float p = v.x * v.x + v.y * v.y;
  #pragma unroll
  for (int off = 1; off < 64; off <<= 1) p += __shfl_xor(p, off);
  if (lane == 0) xx[row] = p;
  u16 h0 = f2bf_rn(v.x);
  u16 l0 = f2bf_rn(v.x - __uint_as_float(((uint32_t)h0) << 16));
  u16 h1 = f2bf_rn(v.y);
  u16 l1 = f2bf_rn(v.y - __uint_as_float(((uint32_t)h1) << 16));
  size_t o = (size_t)row * DD + lane * 2;
  *(uint32_t*)(xh + o) = (uint32_t)h0 | ((uint32_t)h1 << 16);
  *(uint32_t*)(xl + o) = (uint32_t)l0 | ((uint32_t)l1 << 16);
}

// ---------------- Kernel 2: dual GEMM  s = x@Ws, y = x@Wn ----------------
// grid 512 = 256 row-tiles x 2 col-halves; LDS 64KB -> 2 blocks/CU.
__global__ __launch_bounds__(256, 2) void k_gemm(const float* __restrict__ x,
                                                 const float* __restrict__ Ws,
                                                 const float* __restrict__ Wn,
                                                 const float* __restrict__ bias,
                                                 float* __restrict__ hbase,
                                                 float* __restrict__ y) {
  __shared__ __align__(16) float xt[128 * 64];    // [k][r]  32 KB
  __shared__ __align__(16) float wt[128 * 64];    // [k][c-half] 32 KB
  int tid = threadIdx.x;
  int ch = blockIdx.x & 1;
  size_t r0 = (size_t)(blockIdx.x >> 1) * 64;

  { // stage x transposed
    int rr = tid >> 2, kp = (tid & 3) << 5;
    const float* src = x + (r0 + rr) * DD + kp;
    #pragma unroll
    for (int q = 0; q < 8; ++q) {
      float4 v = *(const float4*)(src + (q << 2));
      int k = kp + (q << 2);
      xt[(k + 0) * 64 + rr] = v.x; xt[(k + 1) * 64 + rr] = v.y;
      xt[(k + 2) * 64 + rr] = v.z; xt[(k + 3) * 64 + rr] = v.w;
    }
  }
  { // stage Ws col-half
    const float4* s4 = (const float4*)Ws;
    float4* w4 = (float4*)wt;
    #pragma unroll
    for (int q = 0; q < 8; ++q) {
      int idx = q * 256 + tid;
      w4[idx] = s4[((idx >> 4) << 5) + (ch << 4) + (idx & 15)];
    }
  }
  __syncthreads();

  int tc = tid & 15, tr = tid >> 4;
  float accS[4][4], accY[4][4];
  #pragma unroll
  for (int i = 0; i < 4; ++i)
    #pragma unroll
    for (int u = 0; u < 4; ++u) { accS[i][u] = 0.f; accY[i][u] = 0.f; }

  #pragma unroll 4
  for (int k = 0; k < 128; ++k) {
    float4 a4 = *(const float4*)(xt + k * 64 + (tr << 2));
    float4 w4 = *(const float4*)(wt + k * 64 + (tc << 2));
    float aa[4] = {a4.x, a4.y, a4.z, a4.w};
    float ww[4] = {w4.x, w4.y, w4.z, w4.w};
    #pragma unroll
    for (int i = 0; i < 4; ++i)
      #pragma unroll
      for (int u = 0; u < 4; ++u) accS[i][u] = fmaf(aa[i], ww[u], accS[i][u]);
  }
  __syncthreads();
  { // stage Wn col-half
    const float4* s4 = (const float4*)Wn;
    float4* w4 = (float4*)wt;
    #pragma unroll
    for (int q = 0; q < 8; ++q) {
      int idx = q * 256 + tid;
      w4[idx] = s4[((idx >> 4) << 5) + (ch << 4) + (idx & 15)];
    }
  }
  __syncthreads();
  #pragma unroll 4
  for (int k = 0; k < 128; ++k) {
    float4 a4 = *(const float4*)(xt + k * 64 + (tr << 2));
    float4 w4 = *(const float4*)(wt + k * 64 + (tc << 2));
    float aa[4] = {a4.x, a4.y, a4.z, a4.w};
    float ww[4] = {w4.x, w4.y, w4.z, w4.w};
    #pragma unroll
    for (int i = 0; i < 4; ++i)
      #pragma unroll
      for (int u = 0; u < 4; ++u) accY[i][u] = fmaf(aa[i], ww[u], accY[i][u]);
  }

  int cg = (ch << 6) + (tc << 2);
  float4 bv = *(const float4*)(bias + cg);
  float bb[4] = {bv.x, bv.y, bv.z, bv.w};
  #pragma unroll
  for (int i = 0; i < 4; ++i) {
    size_t row = r0 + (tr << 2) + i;
    float h[4];
    #pragma unroll
    for (int u = 0; u < 4; ++u) h[u] = (accS[i][u] + accY[i][u]) + bb[u];
    *(float4*)(y + row * DD + cg)     = make_float4(accY[i][0], accY[i][1], accY[i][2], accY[i][3]);
    *(float4*)(hbase + row * DD + cg) = make_float4(h[0], h[1], h[2], h[3]);
  }
}

// ---------------- Kernel 3: MFMA pairwise dist SCREEN (approx top-8/split) ----
// grid 1024 = 8 batches (XCD-affine) x 32 n-groups(64) x 4 m-splits(512).
// block 256 = 4 waves; LDS 34 KB -> 4 blocks/CU. 16 chunks of 32 m-rows via
// global_load_lds double-buffer. Selection: SORT8 + MERGE8, branchless.
// (UNCHANGED from round 12 — known-passing screen.)
#define GLOAD(MC, BUF) do { \
    _Pragma("unroll") \
    for (int q = 0; q < 4; ++q) { \
      int ks_ = ((q & 1) << 2) + sks; \
      int mrow_ = mbase + ((MC) << 5) + ((q >> 1) << 4) + sr; \
      const u16* src_ = (ks_ < 4 ? xhb : xlb) + ((size_t)mrow_ << 7) + ((ks_ & 3) << 5) + (sg << 3); \
      gload16(src_, (char*)(&Bc[(BUF)][0]) + (((q << 8) + tid) << 4)); \
    } } while (0)

__global__ __launch_bounds__(256, 4) void k_knn(const u16* __restrict__ xh,
                                                const u16* __restrict__ xl,
                                                const float* __restrict__ xx,
                                                u32* __restrict__ cand) {
  __shared__ __align__(16) u16 Bc[2][8192];   // 2 x 16 KB chunk buffers (32 m-rows)
  __shared__ float xxm[512];

  int tid = threadIdx.x;
  int lane = tid & 63, w = tid >> 6;
  int b = blockIdx.x & 7;                    // XCD-affine batch
  int rest = blockIdx.x >> 3;
  int n0 = (rest & 31) << 6;
  int msplit = rest >> 5;
  int mbase = msplit << 9;
  const u16*  xhb = xh + (((size_t)b << 11) << 7);
  const u16*  xlb = xl + (((size_t)b << 11) << 7);
  const float* xxb = xx + ((size_t)b << 11);

  // staging decode: tid = sks*64 + sg*16 + sr
  int sr = tid & 15, sg = (tid >> 4) & 3, sks = (tid >> 6) & 3;

  GLOAD(0, 0);                // async: chunk 0 -> Bc[0]

  { // stage xx for this m-range
    float2 t = *(const float2*)(xxb + mbase + tid * 2);
    xxm[tid * 2] = t.x; xxm[tid * 2 + 1] = t.y;
  }

  int r = lane & 15, g = lane >> 4;
  int myn = n0 + (w << 4) + r;
  float xxn = xxb[myn];

  // A-side (n) frags hoisted
  bf16x8 ah[4], al[4];
  #pragma unroll
  for (int ks = 0; ks < 4; ++ks) {
    ah[ks] = *(const bf16x8*)(xhb + ((size_t)myn << 7) + (ks << 5) + (g << 3));
    al[ks] = *(const bf16x8*)(xlb + ((size_t)myn << 7) + (ks << 5) + (g << 3));
  }

  u32 t8[8];
  #pragma unroll
  for (int q = 0; q < 8; ++q) t8[q] = 0xFFFFFFFFu;

  __syncthreads();            // vmcnt(0): chunk 0 landed; xxm visible

  int cur = 0;
  for (int mc = 0; mc < 16; ++mc) {
    if (mc < 15) GLOAD(mc + 1, cur ^ 1);     // async into other buffer
    const u16* Bcur = &Bc[cur][0];
    u32 cds[8];
    #pragma unroll
    for (int p = 0; p < 2; ++p) {
      f32x4 ahh = {0.f, 0.f, 0.f, 0.f};
      f32x4 alh = {0.f, 0.f, 0.f, 0.f};
      f32x4 ahl = {0.f, 0.f, 0.f, 0.f};
      #pragma unroll
      for (int ks = 0; ks < 4; ++ks) {
        const u16* base = Bcur + (((p << 3) + ks) << 9) + (lane << 3);
        bf16x8 bh = *(const bf16x8*)(base);
        bf16x8 bo = *(const bf16x8*)(base + 2048);
        ahh = __builtin_amdgcn_mfma_f32_16x16x32_bf16(bh, ah[ks], ahh, 0, 0, 0);
        alh = __builtin_amdgcn_mfma_f32_16x16x32_bf16(bo, ah[ks], alh, 0, 0, 0);
        ahl = __builtin_amdgcn_mfma_f32_16x16x32_bf16(bh, al[ks], ahl, 0, 0, 0);
      }
      float4 xm4 = *(const float4*)(xxm + (mc << 5) + (p << 4) + (g << 2));
      float sx[4] = {xxn + xm4.x, xxn + xm4.y, xxn + xm4.z, xxn + xm4.w};
      int mb0 = mbase + (mc << 5) + (p << 4) + (g << 2);
      #pragma unroll
      for (int e = 0; e < 4; ++e) {
        float dot = (ahh[e] + alh[e]) + ahl[e];
        float d = fmaxf(fmaf(-2.f, dot, sx[e]), 0.f);
        int m = mb0 + e;
        u32 cd = (__float_as_uint(d) & 0xFFFFF000u) | (u32)m;
        cds[(p << 2) + e] = (m == myn) ? 0xFFFFFFFFu : cd;
      }
    }
    SORT8(cds);
    MERGE8(t8, cds);
    __syncthreads();          // all waves done reading Bc[cur]; next chunk landed
    cur ^= 1;
  }

  // merge the 4 g-lanes of each n (each stored list is sorted ascending)
  u32* mbuf = (u32*)(&Bc[0][0]);   // 64 n * 4 g * 8 u32 = 8 KB
  #pragma unroll
  for (int q = 0; q < 8; ++q)
    mbuf[((((w << 4) + r) << 5)) + (g << 3) + q] = t8[q];
  __syncthreads();
  if (g == 0) {
    for (int j = 1; j < 4; ++j) {
      u32 s8[8];
      #pragma unroll
      for (int q = 0; q < 8; ++q)
        s8[q] = mbuf[((((w << 4) + r) << 5)) + (j << 3) + q];
      MERGE8(t8, s8);
    }
    u32* cp = cand + ((((size_t)b << 11) + myn) << 5) + (msplit << 3);
    #pragma unroll
    for (int q = 0; q < 8; ++q) cp[q] = t8[q];
  }
}

// ---------------- Kernel 3b: EXACT f32 rescore — r12-identical arithmetic,
// coalesced via LDS staging. Block = 8 rows; 4 iterations of {phase 1:
// all 256 threads gather 2 rows x 32 cand-rows (32 KB) with contiguous
// 128B-per-thread slices; phase 2: wave 0 (64 thr) computes the EXACT
// round-12 8-chain dot reading xm from LDS (bit-identical values & op
// order -> bit-identical nbr to the passing round-12 kernel).
__global__ __launch_bounds__(256) void k_rsc(const float* __restrict__ x,
                                             const float* __restrict__ xx,
                                             const u32* __restrict__ cand,
                                             int* __restrict__ nbr) {
  __shared__ __align__(16) float xs[2][32][132];   // 33.8 KB, [132] pad: 16B-aligned rows
  __shared__ ull ex[2][32];
  int tid = threadIdx.x;
  int batch = blockIdx.x & 7;            // XCD-affine batch
  int within = blockIdx.x >> 3;          // 0..255
  int r0 = (batch << 11) + (within << 3);
  const float* xb = x + ((size_t)batch << 11) * DD;

  int slot = tid >> 2, part = tid & 3;   // phase-1 roles: 64 slots x 4 parts
  int s_row2 = slot >> 5, s_c = slot & 31;
  int row2c = tid >> 5, c2 = tid & 31;   // phase-2 roles (tid < 64)

  for (int ip = 0; ip < 4; ++ip) {
    { // ---- phase 1: coalesced gather ----
      int row = r0 + (ip << 1) + s_row2;
      u32 cd = cand[((size_t)row << 5) + s_c];
      int m = (int)(cd & 0xFFFu);
      const float* src = xb + (size_t)m * DD + (part << 5);
      float* dst = &xs[s_row2][s_c][part << 5];
      #pragma unroll
      for (int q = 0; q < 8; ++q)
        *(float4*)(dst + (q << 2)) = *(const float4*)(src + (q << 2));
    }
    __syncthreads();
    // ---- phase 2: round-12-identical dot + pack (wave 0 only) ----
    if (tid < 64) {
      int row = r0 + (ip << 1) + row2c;
      u32 cd32 = cand[((size_t)row << 5) + c2];
      int m = (int)(cd32 & 0xFFFu);
      const float* xn = x + (size_t)row * DD;
      const float* xm = &xs[row2c][c2][0];
      float acc[8] = {0.f, 0.f, 0.f, 0.f, 0.f, 0.f, 0.f, 0.f};
      #pragma unroll
      for (int d8 = 0; d8 < 16; ++d8) {
        float4 a0 = *(const float4*)(xn + (d8 << 3));
        float4 a1 = *(const float4*)(xn + (d8 << 3) + 4);
        float4 v0 = *(const float4*)(xm + (d8 << 3));
        float4 v1 = *(const float4*)(xm + (d8 << 3) + 4);
        acc[0] = fmaf(a0.x, v0.x, acc[0]);
        acc[1] = fmaf(a0.y, v0.y, acc[1]);
        acc[2] = fmaf(a0.z, v0.z, acc[2]);
        acc[3] = fmaf(a0.w, v0.w, acc[3]);
        acc[4] = fmaf(a1.x, v1.x, acc[4]);
        acc[5] = fmaf(a1.y, v1.y, acc[5]);
        acc[6] = fmaf(a1.z, v1.z, acc[6]);
        acc[7] = fmaf(a1.w, v1.w, acc[7]);
      }
      float dot = ((acc[0] + acc[1]) + (acc[2] + acc[3])) +
                  ((acc[4] + acc[5]) + (acc[6] + acc[7]));
      float dist = fmaxf((xx[row] - 2.f * dot) + xx[(batch << 11) + m], 0.f);
      ex[row2c][c2] = (((ull)__float_as_uint(dist)) << 32) | (unsigned)m;
    }
    __syncthreads();
    if (tid < 64 && c2 == 0) {       // threads 0 and 32: select per row
      ull t8[8];
      #pragma unroll
      for (int q = 0; q < 8; ++q) t8[q] = ~0ull;
      #pragma unroll
      for (int q = 0; q < 32; ++q) {
        ull v = ex[row2c][q];
        if (v < t8[7]) INS8(t8, v);
      }
      int row = r0 + (ip << 1) + row2c;
      int* op = nbr + (size_t)row * 8;
      #pragma unroll
      for (int q = 0; q < 8; ++q) op[q] = (int)(t8[q] & 0xffffffffu);
    }
    __syncthreads();                 // before next iter overwrites xs/ex
  }
}

// ---------------- Kernel 4: gather + KAN rational + BN partial sums ----------------
// XCD-affine: all 64 blocks of a batch share one XCD's L2 (y slice = 1 MB).
__global__ __launch_bounds__(256) void k_kan(const float* __restrict__ hbase,
                                             const float* __restrict__ y,
                                             const int* __restrict__ nbr,
                                             const float* __restrict__ kan_a,
                                             const float* __restrict__ kan_b,
                                             float* __restrict__ hkan,
                                             double* __restrict__ sums) {
  __shared__ double redA[256], redB[256];
  int f = threadIdx.x & 127;
  int half = threadIdx.x >> 7;
  int batch = blockIdx.x & 7;
  int within = blockIdx.x >> 3;      // 0..63
  int r0 = (batch << 11) + (within << 5) + half * 16;
  const float* yb = y + ((size_t)batch << 11) * DD;
  float a0 = kan_a[f * 3 + 0], a1 = kan_a[f * 3 + 1], a2 = kan_a[f * 3 + 2];
  float b0 = kan_b[f * 2 + 0], b1 = kan_b[f * 2 + 1];
  float disf = (float)(1.0 / sqrt((double)(8.0f + 1e-6f)));
  float cf = disf * disf;
  double sh = 0.0, sh2 = 0.0;
  for (int i = 0; i < 16; ++i) {
    int r = r0 + i;
    const int* np_ = nbr + (size_t)r * 8;
    float t = 0.f;
    #pragma unroll
    for (int j = 0; j < 8; ++j) {
      int m = np_[j];
      float yv = yb[(size_t)m * DD + f];
      t = fmaf(cf, yv, t);
    }
    float h = hbase[(size_t)r * DD + f] + t;
    float h2 = h * h;
    float num = (a0 + a1 * h) + a2 * h2;
    float den = 1.0f + fabsf(b0 * h + b1 * h2);
    float hk = num / (den + 1e-8f);
    hkan[(size_t)r * DD + f] = hk;
    sh += (double)hk; sh2 += (double)hk * (double)hk;
  }
  redA[threadIdx.x] = sh; redB[threadIdx.x] = sh2;
  __syncthreads();
  if (half == 0) {
    atomicAdd(&sums[f], sh + redA[f + 128]);
    atomicAdd(&sums[128 + f], sh2 + redB[f + 128]);
  }
}

// ---------------- Kernel 5: BN finalize + normalize ----------------
__global__ __launch_bounds__(256) void k_bn(const float* __restrict__ hkan,
                                            const double* __restrict__ sums,
                                            const float* __restrict__ gamma,
                                            const float* __restrict__ beta,
                                            float* __restrict__ out) {
  __shared__ float mn[128], sc[128], bt[128];
  int tid = threadIdx.x;
  if (tid < 128) {
    double M = (double)(BB * NN);
    double mean = sums[tid] / M;
    double var = sums[128 + tid] / M - mean * mean;
    if (var < 0.0) var = 0.0;
    mn[tid] = (float)mean;
    sc[tid] = (float)(1.0 / sqrt(var + 1e-5)) * gamma[tid];
    bt[tid] = beta[tid];
  }
  __syncthreads();
  const int total4 = BB * NN * DD / 4;
  for (int i4 = blockIdx.x * blockDim.x + threadIdx.x; i4 < total4;
       i4 += gridDim.x * blockDim.x) {
    float4 v = ((const float4*)hkan)[i4];
    int fb = (i4 * 4) & 127;
    float4 o;
    o.x = (v.x - mn[fb + 0]) * sc[fb + 0] + bt[fb + 0];
    o.y = (v.y - mn[fb + 1]) * sc[fb + 1] + bt[fb + 1];
    o.z = (v.z - mn[fb + 2]) * sc[fb + 2] + bt[fb + 2];
    o.w = (v.w - mn[fb + 3]) * sc[fb + 3] + bt[fb + 3];
    ((float4*)out)[i4] = o;
  }
}

extern "C" void kernel_launch(void* const* d_in, const int* in_sizes, int n_in,
                              void* d_out, int out_size, void* d_ws, size_t ws_size,
                              hipStream_t stream) {
  const float* x     = (const float*)d_in[0];
  const float* Ws    = (const float*)d_in[1];
  const float* Wn    = (const float*)d_in[2];
  const float* ka    = (const float*)d_in[3];
  const float* kb    = (const float*)d_in[4];
  const float* bias  = (const float*)d_in[5];
  const float* gamma = (const float*)d_in[6];
  const float* beta  = (const float*)d_in[7];
  float* out = (float*)d_out;

  char* ws = (char*)d_ws;
  float*  xx    = (float*)(ws + 0);          //  64 KB
  int*    nbr   = (int*)(ws + 65536);        // 512 KB
  double* sums  = (double*)(ws + 589824);    //   2 KB
  float*  y     = (float*)(ws + 1048576);    //   8 MB
  float*  hbase = (float*)(ws + 9437184);    //   8 MB
  float*  hkan  = (float*)(ws + 17825792);   //   8 MB (aliased below until k_kan)
  u32*    cand  = (u32*)(ws + 17825792);     //   2 MB (dead before k_kan writes hkan)
  u16*    xh    = (u16*)(ws + 22020096);     //   4 MB (dead before k_kan writes hkan)
  u16*    xl    = (u16*)d_out;               //   4 MB scratch in d_out; k_bn overwrites d_out last

  hipMemsetAsync(sums, 0, 256 * sizeof(double), stream);
  k_cvx <<<4096, 256, 0, stream>>>(x, xx, xh, xl);
  k_gemm<<<512,  256, 0, stream>>>(x, Ws, Wn, bias, hbase, y);
  k_knn <<<1024, 256, 0, stream>>>(xh, xl, xx, cand);
  k_rsc <<<2048, 256, 0, stream>>>(x, xx, cand, nbr);
  k_kan <<<512,  256, 0, stream>>>(hbase, y, nbr, ka, kb, hkan, sums);
  k_bn  <<<1024, 256, 0, stream>>>(hkan, sums, gamma, beta, out);
}

// Round 15
// 131.825 us; speedup vs baseline: 1.4874x; 1.4874x over previous
//
#include <hip/hip_runtime.h>
#include <stdint.h>

#define BB 8
#define NN 2048
#define DD 128

typedef unsigned long long ull;
typedef unsigned int u32;
typedef unsigned short u16;
typedef __attribute__((ext_vector_type(8))) short bf16x8;
typedef __attribute__((ext_vector_type(4))) float f32x4;

// insertion into sorted-ascending 8-slot u64 register array (static indices only)
#define INS8(t8, cand) do { \
    t8[7] = (cand); ull _t; \
    if (t8[7] < t8[6]) { _t = t8[6]; t8[6] = t8[7]; t8[7] = _t; } \
    if (t8[6] < t8[5]) { _t = t8[5]; t8[5] = t8[6]; t8[6] = _t; } \
    if (t8[5] < t8[4]) { _t = t8[4]; t8[4] = t8[5]; t8[5] = _t; } \
    if (t8[4] < t8[3]) { _t = t8[3]; t8[3] = t8[4]; t8[4] = _t; } \
    if (t8[3] < t8[2]) { _t = t8[2]; t8[2] = t8[3]; t8[3] = _t; } \
    if (t8[2] < t8[1]) { _t = t8[1]; t8[1] = t8[2]; t8[2] = _t; } \
    if (t8[1] < t8[0]) { _t = t8[0]; t8[0] = t8[1]; t8[1] = _t; } \
  } while (0)

// compare-exchange (emits v_min_u32/v_max_u32, branchless)
#define CEX(a, b) do { u32 _lo = (a) < (b) ? (a) : (b); \
                       u32 _hi = (a) < (b) ? (b) : (a); \
                       (a) = _lo; (b) = _hi; } while (0)

// Batcher sort of 8 (19 CE): sort4 + sort4 + odd-even merge
#define SORT8(c) do { \
    CEX(c[0], c[1]); CEX(c[2], c[3]); CEX(c[0], c[2]); CEX(c[1], c[3]); CEX(c[1], c[2]); \
    CEX(c[4], c[5]); CEX(c[6], c[7]); CEX(c[4], c[6]); CEX(c[5], c[7]); CEX(c[5], c[6]); \
    CEX(c[0], c[4]); CEX(c[1], c[5]); CEX(c[2], c[6]); CEX(c[3], c[7]); \
    CEX(c[2], c[4]); CEX(c[3], c[5]); \
    CEX(c[1], c[2]); CEX(c[3], c[4]); CEX(c[5], c[6]); } while (0)

// t (sorted asc) := lowest-8 of union(t, s) (s sorted asc), sorted asc.
#define MERGE8(t, s) do { \
    u32 m0_ = (t)[0] < (s)[7] ? (t)[0] : (s)[7]; \
    u32 m1_ = (t)[1] < (s)[6] ? (t)[1] : (s)[6]; \
    u32 m2_ = (t)[2] < (s)[5] ? (t)[2] : (s)[5]; \
    u32 m3_ = (t)[3] < (s)[4] ? (t)[3] : (s)[4]; \
    u32 m4_ = (t)[4] < (s)[3] ? (t)[4] : (s)[3]; \
    u32 m5_ = (t)[5] < (s)[2] ? (t)[5] : (s)[2]; \
    u32 m6_ = (t)[6] < (s)[1] ? (t)[6] : (s)[1]; \
    u32 m7_ = (t)[7] < (s)[0] ? (t)[7] : (s)[0]; \
    CEX(m0_, m4_); CEX(m1_, m5_); CEX(m2_, m6_); CEX(m3_, m7_); \
    CEX(m0_, m2_); CEX(m1_, m3_); CEX(m4_, m6_); CEX(m5_, m7_); \
    CEX(m0_, m1_); CEX(m2_, m3_); CEX(m4_, m5_); CEX(m6_, m7_); \
    (t)[0] = m0_; (t)[1] = m1_; (t)[2] = m2_; (t)[3] = m3_; \
    (t)[4] = m4_; (t)[5] = m5_; (t)[6] = m6_; (t)[7] = m7_; \
  } while (0)

// bitonic merge: c[16] = (asc 8, desc 8) -> sorted asc 16
#define BMERGE16(c) do { \
    _Pragma("unroll") for (int _i = 0; _i < 8; ++_i) CEX(c[_i], c[_i + 8]); \
    _Pragma("unroll") for (int _g = 0; _g < 16; _g += 8) \
      _Pragma("unroll") for (int _i = 0; _i < 4; ++_i) CEX(c[_g + _i], c[_g + _i + 4]); \
    _Pragma("unroll") for (int _g = 0; _g < 16; _g += 4) \
      _Pragma("unroll") for (int _i = 0; _i < 2; ++_i) CEX(c[_g + _i], c[_g + _i + 2]); \
    _Pragma("unroll") for (int _g = 0; _g < 16; _g += 2) CEX(c[_g], c[_g + 1]); \
  } while (0)

__device__ inline u16 f2bf_rn(float f) {
  uint32_t u = __float_as_uint(f);
  return (u16)((u + 0x7fffu + ((u >> 16) & 1u)) >> 16);
}

typedef __attribute__((address_space(1))) const void gvoid_t;
typedef __attribute__((address_space(3))) void lvoid_t;
__device__ __forceinline__ void gload16(const void* g, void* l) {
  __builtin_amdgcn_global_load_lds((gvoid_t*)g, (lvoid_t*)l, 16, 0, 0);
}

// ---------------- Kernel 1: fused  xx[row] = sum x^2  +  bf16 hi/lo split ----
__global__ __launch_bounds__(256) void k_cvx(const float* __restrict__ x,
                                             float* __restrict__ xx,
                                             u16* __restrict__ xh,
                                             u16* __restrict__ xl) {
  int row  = blockIdx.x * 4 + (threadIdx.x >> 6);
  int lane = threadIdx.x & 63;
  float2 v = *reinterpret_cast<const float2*>(x + (size_t)row * DD + lane * 2);
  float p = v.x * v.x + v.y * v.y;
  #pragma unroll
  for (int off = 1; off < 64; off <<= 1) p += __shfl_xor(p, off);
  if (lane == 0) xx[row] = p;
  u16 h0 = f2bf_rn(v.x);
  u16 l0 = f2bf_rn(v.x - __uint_as_float(((uint32_t)h0) << 16));
  u16 h1 = f2bf_rn(v.y);
  u16 l1 = f2bf_rn(v.y - __uint_as_float(((uint32_t)h1) << 16));
  size_t o = (size_t)row * DD + lane * 2;
  *(uint32_t*)(xh + o) = (uint32_t)h0 | ((uint32_t)h1 << 16);
  *(uint32_t*)(xl + o) = (uint32_t)l0 | ((uint32_t)l1 << 16);
}

// ---------------- Kernel 2: dual GEMM  s = x@Ws, y = x@Wn ----------------
// grid 512 = 256 row-tiles x 2 col-halves; LDS 64KB -> 2 blocks/CU.
__global__ __launch_bounds__(256, 2) void k_gemm(const float* __restrict__ x,
                                                 const float* __restrict__ Ws,
                                                 const float* __restrict__ Wn,
                                                 const float* __restrict__ bias,
                                                 float* __restrict__ hbase,
                                                 float* __restrict__ y) {
  __shared__ __align__(16) float xt[128 * 64];    // [k][r]  32 KB
  __shared__ __align__(16) float wt[128 * 64];    // [k][c-half] 32 KB
  int tid = threadIdx.x;
  int ch = blockIdx.x & 1;
  size_t r0 = (size_t)(blockIdx.x >> 1) * 64;

  { // stage x transposed
    int rr = tid >> 2, kp = (tid & 3) << 5;
    const float* src = x + (r0 + rr) * DD + kp;
    #pragma unroll
    for (int q = 0; q < 8; ++q) {
      float4 v = *(const float4*)(src + (q << 2));
      int k = kp + (q << 2);
      xt[(k + 0) * 64 + rr] = v.x; xt[(k + 1) * 64 + rr] = v.y;
      xt[(k + 2) * 64 + rr] = v.z; xt[(k + 3) * 64 + rr] = v.w;
    }
  }
  { // stage Ws col-half
    const float4* s4 = (const float4*)Ws;
    float4* w4 = (float4*)wt;
    #pragma unroll
    for (int q = 0; q < 8; ++q) {
      int idx = q * 256 + tid;
      w4[idx] = s4[((idx >> 4) << 5) + (ch << 4) + (idx & 15)];
    }
  }
  __syncthreads();

  int tc = tid & 15, tr = tid >> 4;
  float accS[4][4], accY[4][4];
  #pragma unroll
  for (int i = 0; i < 4; ++i)
    #pragma unroll
    for (int u = 0; u < 4; ++u) { accS[i][u] = 0.f; accY[i][u] = 0.f; }

  #pragma unroll 4
  for (int k = 0; k < 128; ++k) {
    float4 a4 = *(const float4*)(xt + k * 64 + (tr << 2));
    float4 w4 = *(const float4*)(wt + k * 64 + (tc << 2));
    float aa[4] = {a4.x, a4.y, a4.z, a4.w};
    float ww[4] = {w4.x, w4.y, w4.z, w4.w};
    #pragma unroll
    for (int i = 0; i < 4; ++i)
      #pragma unroll
      for (int u = 0; u < 4; ++u) accS[i][u] = fmaf(aa[i], ww[u], accS[i][u]);
  }
  __syncthreads();
  { // stage Wn col-half
    const float4* s4 = (const float4*)Wn;
    float4* w4 = (float4*)wt;
    #pragma unroll
    for (int q = 0; q < 8; ++q) {
      int idx = q * 256 + tid;
      w4[idx] = s4[((idx >> 4) << 5) + (ch << 4) + (idx & 15)];
    }
  }
  __syncthreads();
  #pragma unroll 4
  for (int k = 0; k < 128; ++k) {
    float4 a4 = *(const float4*)(xt + k * 64 + (tr << 2));
    float4 w4 = *(const float4*)(wt + k * 64 + (tc << 2));
    float aa[4] = {a4.x, a4.y, a4.z, a4.w};
    float ww[4] = {w4.x, w4.y, w4.z, w4.w};
    #pragma unroll
    for (int i = 0; i < 4; ++i)
      #pragma unroll
      for (int u = 0; u < 4; ++u) accY[i][u] = fmaf(aa[i], ww[u], accY[i][u]);
  }

  int cg = (ch << 6) + (tc << 2);
  float4 bv = *(const float4*)(bias + cg);
  float bb[4] = {bv.x, bv.y, bv.z, bv.w};
  #pragma unroll
  for (int i = 0; i < 4; ++i) {
    size_t row = r0 + (tr << 2) + i;
    float h[4];
    #pragma unroll
    for (int u = 0; u < 4; ++u) h[u] = (accS[i][u] + accY[i][u]) + bb[u];
    *(float4*)(y + row * DD + cg)     = make_float4(accY[i][0], accY[i][1], accY[i][2], accY[i][3]);
    *(float4*)(hbase + row * DD + cg) = make_float4(h[0], h[1], h[2], h[3]);
  }
}

// ---------------- Kernel 3: MFMA pairwise dist SCREEN (approx top-8/split) ----
// grid 1024 = 8 batches (XCD-affine) x 32 n-groups(64) x 4 m-splits(512).
// block 256 = 4 waves; LDS 34 KB -> 4 blocks/CU. 16 chunks of 32 m-rows via
// global_load_lds double-buffer. Selection: chunk-min early-skip (exact:
// MERGE8 would be a no-op when cmin >= t8[7]) + SORT8 + MERGE8, branchless.
// Quantized key = (dist & 0xFFFFF800) | m  (11-bit m, step 2x finer than r12).
#define GLOAD(MC, BUF) do { \
    _Pragma("unroll") \
    for (int q = 0; q < 4; ++q) { \
      int ks_ = ((q & 1) << 2) + sks; \
      int mrow_ = mbase + ((MC) << 5) + ((q >> 1) << 4) + sr; \
      const u16* src_ = (ks_ < 4 ? xhb : xlb) + ((size_t)mrow_ << 7) + ((ks_ & 3) << 5) + (sg << 3); \
      gload16(src_, (char*)(&Bc[(BUF)][0]) + (((q << 8) + tid) << 4)); \
    } } while (0)

__global__ __launch_bounds__(256, 4) void k_knn(const u16* __restrict__ xh,
                                                const u16* __restrict__ xl,
                                                const float* __restrict__ xx,
                                                u32* __restrict__ cand) {
  __shared__ __align__(16) u16 Bc[2][8192];   // 2 x 16 KB chunk buffers (32 m-rows)
  __shared__ float xxm[512];

  int tid = threadIdx.x;
  int lane = tid & 63, w = tid >> 6;
  int b = blockIdx.x & 7;                    // XCD-affine batch
  int rest = blockIdx.x >> 3;
  int n0 = (rest & 31) << 6;
  int msplit = rest >> 5;
  int mbase = msplit << 9;
  const u16*  xhb = xh + (((size_t)b << 11) << 7);
  const u16*  xlb = xl + (((size_t)b << 11) << 7);
  const float* xxb = xx + ((size_t)b << 11);

  // staging decode: tid = sks*64 + sg*16 + sr
  int sr = tid & 15, sg = (tid >> 4) & 3, sks = (tid >> 6) & 3;

  GLOAD(0, 0);                // async: chunk 0 -> Bc[0]

  { // stage xx for this m-range
    float2 t = *(const float2*)(xxb + mbase + tid * 2);
    xxm[tid * 2] = t.x; xxm[tid * 2 + 1] = t.y;
  }

  int r = lane & 15, g = lane >> 4;
  int myn = n0 + (w << 4) + r;
  float xxn = xxb[myn];

  // A-side (n) frags hoisted
  bf16x8 ah[4], al[4];
  #pragma unroll
  for (int ks = 0; ks < 4; ++ks) {
    ah[ks] = *(const bf16x8*)(xhb + ((size_t)myn << 7) + (ks << 5) + (g << 3));
    al[ks] = *(const bf16x8*)(xlb + ((size_t)myn << 7) + (ks << 5) + (g << 3));
  }

  u32 t8[8];
  #pragma unroll
  for (int q = 0; q < 8; ++q) t8[q] = 0xFFFFFFFFu;

  __syncthreads();            // vmcnt(0): chunk 0 landed; xxm visible

  int cur = 0;
  for (int mc = 0; mc < 16; ++mc) {
    if (mc < 15) GLOAD(mc + 1, cur ^ 1);     // async into other buffer
    const u16* Bcur = &Bc[cur][0];
    u32 cds[8];
    #pragma unroll
    for (int p = 0; p < 2; ++p) {
      f32x4 ahh = {0.f, 0.f, 0.f, 0.f};
      f32x4 alh = {0.f, 0.f, 0.f, 0.f};
      f32x4 ahl = {0.f, 0.f, 0.f, 0.f};
      #pragma unroll
      for (int ks = 0; ks < 4; ++ks) {
        const u16* base = Bcur + (((p << 3) + ks) << 9) + (lane << 3);
        bf16x8 bh = *(const bf16x8*)(base);
        bf16x8 bo = *(const bf16x8*)(base + 2048);
        ahh = __builtin_amdgcn_mfma_f32_16x16x32_bf16(bh, ah[ks], ahh, 0, 0, 0);
        alh = __builtin_amdgcn_mfma_f32_16x16x32_bf16(bo, ah[ks], alh, 0, 0, 0);
        ahl = __builtin_amdgcn_mfma_f32_16x16x32_bf16(bh, al[ks], ahl, 0, 0, 0);
      }
      float4 xm4 = *(const float4*)(xxm + (mc << 5) + (p << 4) + (g << 2));
      float sx[4] = {xxn + xm4.x, xxn + xm4.y, xxn + xm4.z, xxn + xm4.w};
      int mb0 = mbase + (mc << 5) + (p << 4) + (g << 2);
      #pragma unroll
      for (int e = 0; e < 4; ++e) {
        float dot = (ahh[e] + alh[e]) + ahl[e];
        float d = fmaxf(fmaf(-2.f, dot, sx[e]), 0.f);
        int m = mb0 + e;
        u32 cd = (__float_as_uint(d) & 0xFFFFF800u) | (u32)m;
        cds[(p << 2) + e] = (m == myn) ? 0xFFFFFFFFu : cd;
      }
    }
    { // chunk-min early skip (exact: if cmin >= t8[7], MERGE8 is a no-op)
      u32 c01 = cds[0] < cds[1] ? cds[0] : cds[1];
      u32 c23 = cds[2] < cds[3] ? cds[2] : cds[3];
      u32 c45 = cds[4] < cds[5] ? cds[4] : cds[5];
      u32 c67 = cds[6] < cds[7] ? cds[6] : cds[7];
      u32 c03 = c01 < c23 ? c01 : c23;
      u32 c47 = c45 < c67 ? c45 : c67;
      u32 cmin = c03 < c47 ? c03 : c47;
      if (cmin < t8[7]) {
        SORT8(cds);
        MERGE8(t8, cds);
      }
    }
    __syncthreads();          // all waves done reading Bc[cur]; next chunk landed
    cur ^= 1;
  }

  // merge the 4 g-lanes of each n (each stored list is sorted ascending)
  u32* mbuf = (u32*)(&Bc[0][0]);   // 64 n * 4 g * 8 u32 = 8 KB
  #pragma unroll
  for (int q = 0; q < 8; ++q)
    mbuf[((((w << 4) + r) << 5)) + (g << 3) + q] = t8[q];
  __syncthreads();
  if (g == 0) {
    for (int j = 1; j < 4; ++j) {
      u32 s8[8];
      #pragma unroll
      for (int q = 0; q < 8; ++q)
        s8[q] = mbuf[((((w << 4) + r) << 5)) + (j << 3) + q];
      MERGE8(t8, s8);
    }
    u32* cp = cand + ((((size_t)b << 11) + myn) << 5) + (msplit << 3);
    #pragma unroll
    for (int q = 0; q < 8; ++q) cp[q] = t8[q];
  }
}

// ---------------- Kernel 3b: EXACT f32 rescore of 16 survivors/row --------
// Preamble (1 thread/row): merge the 4 sorted split-lists via bitonic
// MERGE16 networks and keep the lowest-16 of 32 by quantized key (true
// top-8 subset with overwhelming probability). Main: one thread per
// (row, cand) computes the ROUND-12-VERBATIM 8-chain fmaf dot directly
// from global (validated arithmetic & memory pattern); INS8 tie-order.
__global__ __launch_bounds__(256) void k_rsc(const float* __restrict__ x,
                                             const float* __restrict__ xx,
                                             const u32* __restrict__ cand,
                                             int* __restrict__ nbr) {
  __shared__ u32 c16[16][16];
  __shared__ ull ex[16][16];
  int tid = threadIdx.x;
  int rloc = tid >> 4;               // 16 rows per block
  int c = tid & 15;
  int batch = blockIdx.x & 7;        // XCD-affine batch
  int within = blockIdx.x >> 3;      // 0..127
  int row = (batch << 11) + (within << 4) + rloc;

  if (c == 0) {  // merge 4 sorted-8 quantized lists -> lowest-16 set
    const u32* cp = cand + ((size_t)row << 5);
    u32 A[16], B[16];
    #pragma unroll
    for (int q = 0; q < 8; ++q) { A[q] = cp[q];      A[8 + q] = cp[15 - q]; }
    #pragma unroll
    for (int q = 0; q < 8; ++q) { B[q] = cp[16 + q]; B[8 + q] = cp[31 - q]; }
    BMERGE16(A);
    BMERGE16(B);
    #pragma unroll
    for (int i = 0; i < 16; ++i) {
      u32 lo = A[i] < B[15 - i] ? A[i] : B[15 - i];
      c16[rloc][i] = lo & 0x7FFu;
    }
  }
  __syncthreads();

  {
    int m = (int)c16[rloc][c];
    const float* xn = x + (size_t)row * DD;
    const float* xm = x + ((size_t)(batch << 11) + m) * DD;
    float acc[8] = {0.f, 0.f, 0.f, 0.f, 0.f, 0.f, 0.f, 0.f};
    #pragma unroll
    for (int d8 = 0; d8 < 16; ++d8) {
      float4 a0 = *(const float4*)(xn + (d8 << 3));
      float4 a1 = *(const float4*)(xn + (d8 << 3) + 4);
      float4 v0 = *(const float4*)(xm + (d8 << 3));
      float4 v1 = *(const float4*)(xm + (d8 << 3) + 4);
      acc[0] = fmaf(a0.x, v0.x, acc[0]);
      acc[1] = fmaf(a0.y, v0.y, acc[1]);
      acc[2] = fmaf(a0.z, v0.z, acc[2]);
      acc[3] = fmaf(a0.w, v0.w, acc[3]);
      acc[4] = fmaf(a1.x, v1.x, acc[4]);
      acc[5] = fmaf(a1.y, v1.y, acc[5]);
      acc[6] = fmaf(a1.z, v1.z, acc[6]);
      acc[7] = fmaf(a1.w, v1.w, acc[7]);
    }
    float dot = ((acc[0] + acc[1]) + (acc[2] + acc[3])) +
                ((acc[4] + acc[5]) + (acc[6] + acc[7]));
    float dist = fmaxf((xx[row] - 2.f * dot) + xx[(batch << 11) + m], 0.f);
    ex[rloc][c] = (((ull)__float_as_uint(dist)) << 32) | (unsigned)m;
  }
  __syncthreads();
  if (c == 0) {
    ull t8[8];
    #pragma unroll
    for (int q = 0; q < 8; ++q) t8[q] = ~0ull;
    #pragma unroll
    for (int q = 0; q < 16; ++q) {
      ull v = ex[rloc][q];
      if (v < t8[7]) INS8(t8, v);
    }
    int* op = nbr + (size_t)row * 8;
    #pragma unroll
    for (int q = 0; q < 8; ++q) op[q] = (int)(t8[q] & 0xffffffffu);
  }
}

// ---------------- Kernel 4: gather + KAN rational + BN partial sums ----------------
// XCD-affine: all 64 blocks of a batch share one XCD's L2 (y slice = 1 MB).
__global__ __launch_bounds__(256) void k_kan(const float* __restrict__ hbase,
                                             const float* __restrict__ y,
                                             const int* __restrict__ nbr,
                                             const float* __restrict__ kan_a,
                                             const float* __restrict__ kan_b,
                                             float* __restrict__ hkan,
                                             double* __restrict__ sums) {
  __shared__ double redA[256], redB[256];
  int f = threadIdx.x & 127;
  int half = threadIdx.x >> 7;
  int batch = blockIdx.x & 7;
  int within = blockIdx.x >> 3;      // 0..63
  int r0 = (batch << 11) + (within << 5) + half * 16;
  const float* yb = y + ((size_t)batch << 11) * DD;
  float a0 = kan_a[f * 3 + 0], a1 = kan_a[f * 3 + 1], a2 = kan_a[f * 3 + 2];
  float b0 = kan_b[f * 2 + 0], b1 = kan_b[f * 2 + 1];
  float disf = (float)(1.0 / sqrt((double)(8.0f + 1e-6f)));
  float cf = disf * disf;
  double sh = 0.0, sh2 = 0.0;
  for (int i = 0; i < 16; ++i) {
    int r = r0 + i;
    const int* np_ = nbr + (size_t)r * 8;
    float t = 0.f;
    #pragma unroll
    for (int j = 0; j < 8; ++j) {
      int m = np_[j];
      float yv = yb[(size_t)m * DD + f];
      t = fmaf(cf, yv, t);
    }
    float h = hbase[(size_t)r * DD + f] + t;
    float h2 = h * h;
    float num = (a0 + a1 * h) + a2 * h2;
    float den = 1.0f + fabsf(b0 * h + b1 * h2);
    float hk = num / (den + 1e-8f);
    hkan[(size_t)r * DD + f] = hk;
    sh += (double)hk; sh2 += (double)hk * (double)hk;
  }
  redA[threadIdx.x] = sh; redB[threadIdx.x] = sh2;
  __syncthreads();
  if (half == 0) {
    atomicAdd(&sums[f], sh + redA[f + 128]);
    atomicAdd(&sums[128 + f], sh2 + redB[f + 128]);
  }
}

// ---------------- Kernel 5: BN finalize + normalize ----------------
__global__ __launch_bounds__(256) void k_bn(const float* __restrict__ hkan,
                                            const double* __restrict__ sums,
                                            const float* __restrict__ gamma,
                                            const float* __restrict__ beta,
                                            float* __restrict__ out) {
  __shared__ float mn[128], sc[128], bt[128];
  int tid = threadIdx.x;
  if (tid < 128) {
    double M = (double)(BB * NN);
    double mean = sums[tid] / M;
    double var = sums[128 + tid] / M - mean * mean;
    if (var < 0.0) var = 0.0;
    mn[tid] = (float)mean;
    sc[tid] = (float)(1.0 / sqrt(var + 1e-5)) * gamma[tid];
    bt[tid] = beta[tid];
  }
  __syncthreads();
  const int total4 = BB * NN * DD / 4;
  for (int i4 = blockIdx.x * blockDim.x + threadIdx.x; i4 < total4;
       i4 += gridDim.x * blockDim.x) {
    float4 v = ((const float4*)hkan)[i4];
    int fb = (i4 * 4) & 127;
    float4 o;
    o.x = (v.x - mn[fb + 0]) * sc[fb + 0] + bt[fb + 0];
    o.y = (v.y - mn[fb + 1]) * sc[fb + 1] + bt[fb + 1];
    o.z = (v.z - mn[fb + 2]) * sc[fb + 2] + bt[fb + 2];
    o.w = (v.w - mn[fb + 3]) * sc[fb + 3] + bt[fb + 3];
    ((float4*)out)[i4] = o;
  }
}

extern "C" void kernel_launch(void* const* d_in, const int* in_sizes, int n_in,
                              void* d_out, int out_size, void* d_ws, size_t ws_size,
                              hipStream_t stream) {
  const float* x     = (const float*)d_in[0];
  const float* Ws    = (const float*)d_in[1];
  const float* Wn    = (const float*)d_in[2];
  const float* ka    = (const float*)d_in[3];
  const float* kb    = (const float*)d_in[4];
  const float* bias  = (const float*)d_in[5];
  const float* gamma = (const float*)d_in[6];
  const float* beta  = (const float*)d_in[7];
  float* out = (float*)d_out;

  char* ws = (char*)d_ws;
  float*  xx    = (float*)(ws + 0);          //  64 KB
  int*    nbr   = (int*)(ws + 65536);        // 512 KB
  double* sums  = (double*)(ws + 589824);    //   2 KB
  float*  y     = (float*)(ws + 1048576);    //   8 MB
  float*  hbase = (float*)(ws + 9437184);    //   8 MB
  float*  hkan  = (float*)(ws + 17825792);   //   8 MB (aliased below until k_kan)
  u32*    cand  = (u32*)(ws + 17825792);     //   2 MB (dead before k_kan writes hkan)
  u16*    xh    = (u16*)(ws + 22020096);     //   4 MB (dead before k_kan writes hkan)
  u16*    xl    = (u16*)d_out;               //   4 MB scratch in d_out; k_bn overwrites d_out last

  hipMemsetAsync(sums, 0, 256 * sizeof(double), stream);
  k_cvx <<<4096, 256, 0, stream>>>(x, xx, xh, xl);
  k_gemm<<<512,  256, 0, stream>>>(x, Ws, Wn, bias, hbase, y);
  k_knn <<<1024, 256, 0, stream>>>(xh, xl, xx, cand);
  k_rsc <<<1024, 256, 0, stream>>>(x, xx, cand, nbr);
  k_kan <<<512,  256, 0, stream>>>(hbase, y, nbr, ka, kb, hkan, sums);
  k_bn  <<<1024, 256, 0, stream>>>(hkan, sums, gamma, beta, out);
}